// Round 1
// baseline (336.215 us; speedup 1.0000x reference)
//
#include <hip/hip_runtime.h>
#include <hip/hip_bf16.h>

typedef __bf16 bf16x4 __attribute__((ext_vector_type(4)));
typedef __bf16 bf16x8 __attribute__((ext_vector_type(8)));
typedef float  f32x4  __attribute__((ext_vector_type(4)));

constexpr int B = 2, S = 2048, D = 1024, H = 16, DK = 64;
constexpr int M = B * S;   // 4096 projection rows
constexpr int BH = B * H;  // 32

// ---------------- f32 -> bf16 convert (vectorized) ----------------
__global__ __launch_bounds__(256) void convx(const float* __restrict__ in,
                                             __bf16* __restrict__ out, int n) {
  int i = (blockIdx.x * 256 + threadIdx.x) * 4;
  if (i >= n) return;
  float4 v = *(const float4*)(in + i);
  bf16x4 o;
  o[0] = (__bf16)v.x; o[1] = (__bf16)v.y; o[2] = (__bf16)v.z; o[3] = (__bf16)v.w;
  *(bf16x4*)(out + i) = o;
}

// ---------------- W [K][N] f32 -> WT [N][K] bf16 ----------------
__global__ __launch_bounds__(256) void wtrans(const float* __restrict__ W,
                                              __bf16* __restrict__ WT) {
  __shared__ float t[32][33];
  int tx = threadIdx.x & 31, ty0 = threadIdx.x >> 5;  // 32 x 8
  int n0 = blockIdx.x * 32, k0 = blockIdx.y * 32;
#pragma unroll
  for (int i = 0; i < 4; ++i)
    t[ty0 + i * 8][tx] = W[(size_t)(k0 + ty0 + i * 8) * D + n0 + tx];
  __syncthreads();
#pragma unroll
  for (int i = 0; i < 4; ++i)
    WT[(size_t)(n0 + ty0 + i * 8) * D + k0 + tx] = (__bf16)t[tx][ty0 + i * 8];
}

// ---------------- projection GEMM: C = A * WT^T + bias ----------------
// A [M][D] bf16, WT [D(n)][D(k)] bf16 (pre-transposed W), out per mode:
//   mode 0: out[((b*H+h)*S + s)*DK + dk]   (Q / K layout [B,H,S,DK])
//   mode 1: out[((b*H+h)*DK + dk)*S + s]   (V transposed   [B,H,DK,S])
constexpr int TM = 128, TN = 128, BK = 32;

__global__ __launch_bounds__(256) void proj_gemm(const __bf16* __restrict__ A,
                                                 const __bf16* __restrict__ BT,
                                                 const float* __restrict__ bias,
                                                 __bf16* __restrict__ out,
                                                 int mode) {
  __shared__ __align__(16) __bf16 As[TM * BK];
  __shared__ __align__(16) __bf16 Bs[TN * BK];
  int t = threadIdx.x;
  int m0 = blockIdx.y * TM, n0 = blockIdx.x * TN;
  int w = t >> 6, lane = t & 63, c = lane & 15, g = lane >> 4;
  int wr = w >> 1, wc = w & 1;

  f32x4 acc[4][4];
#pragma unroll
  for (int i = 0; i < 4; ++i)
#pragma unroll
    for (int j = 0; j < 4; ++j) acc[i][j] = f32x4{0.f, 0.f, 0.f, 0.f};

  int srow = t >> 2;           // 0..63
  int scol = (t & 3) * 8;      // bf16 col within BK
  const __bf16* ag = A + (size_t)(m0 + srow) * D + scol;
  const __bf16* bg = BT + (size_t)(n0 + srow) * D + scol;

  for (int kk = 0; kk < D; kk += BK) {
    __builtin_amdgcn_global_load_lds(
        (const __attribute__((address_space(1))) unsigned int*)(ag + kk),
        (__attribute__((address_space(3))) unsigned int*)(As + t * 8), 16, 0, 0);
    __builtin_amdgcn_global_load_lds(
        (const __attribute__((address_space(1))) unsigned int*)(ag + (size_t)64 * D + kk),
        (__attribute__((address_space(3))) unsigned int*)(As + 2048 + t * 8), 16, 0, 0);
    __builtin_amdgcn_global_load_lds(
        (const __attribute__((address_space(1))) unsigned int*)(bg + kk),
        (__attribute__((address_space(3))) unsigned int*)(Bs + t * 8), 16, 0, 0);
    __builtin_amdgcn_global_load_lds(
        (const __attribute__((address_space(1))) unsigned int*)(bg + (size_t)64 * D + kk),
        (__attribute__((address_space(3))) unsigned int*)(Bs + 2048 + t * 8), 16, 0, 0);
    __syncthreads();

    bf16x8 af[4], bf[4];
#pragma unroll
    for (int i = 0; i < 4; ++i)
      af[i] = *(const bf16x8*)(As + (wr * 64 + i * 16 + c) * 32 + g * 8);
#pragma unroll
    for (int j = 0; j < 4; ++j)
      bf[j] = *(const bf16x8*)(Bs + (wc * 64 + j * 16 + c) * 32 + g * 8);
#pragma unroll
    for (int i = 0; i < 4; ++i)
#pragma unroll
      for (int j = 0; j < 4; ++j)
        acc[i][j] = __builtin_amdgcn_mfma_f32_16x16x32_bf16(af[i], bf[j], acc[i][j], 0, 0, 0);
    __syncthreads();
  }

  // epilogue: bias + scatter to head layout
#pragma unroll
  for (int i = 0; i < 4; ++i)
#pragma unroll
    for (int j = 0; j < 4; ++j) {
      int n = n0 + wc * 64 + j * 16 + c;
      float bv = bias[n];
      int h = n >> 6, dk = n & 63;
#pragma unroll
      for (int q = 0; q < 4; ++q) {
        int mrow = m0 + wr * 64 + i * 16 + g * 4 + q;
        int b = mrow >> 11, s = mrow & (S - 1);
        float val = acc[i][j][q] + bv;
        size_t idx;
        if (mode == 0) idx = ((size_t)(b * H + h) * S + s) * DK + dk;
        else           idx = ((size_t)(b * H + h) * DK + dk) * S + s;
        out[idx] = (__bf16)val;
      }
    }
}

// ---------------- flash attention ----------------
// Q,K: [BH][S][DK] bf16; VT: [BH][DK][S] bf16; out: [B][S][D] f32
constexpr int QBLK = 64, KVB = 64;

__global__ __launch_bounds__(256) void attn(const __bf16* __restrict__ Q,
                                            const __bf16* __restrict__ K,
                                            const __bf16* __restrict__ VT,
                                            float* __restrict__ out) {
  __shared__ __align__(16) __bf16 P[4][16][72];  // per-wave P tile, padded
  int t = threadIdx.x, w = t >> 6, lane = t & 63, c = lane & 15, g = lane >> 4;
  int bh = blockIdx.y, q0 = blockIdx.x * QBLK;
  const __bf16* Qb = Q + (size_t)bh * S * DK;
  const __bf16* Kb = K + (size_t)bh * S * DK;
  const __bf16* Vb = VT + (size_t)bh * DK * S;

  int qr = q0 + w * 16;
  bf16x8 qf[2];
  qf[0] = *(const bf16x8*)(Qb + (size_t)(qr + c) * DK + g * 8);
  qf[1] = *(const bf16x8*)(Qb + (size_t)(qr + c) * DK + 32 + g * 8);

  float mr[4] = {-INFINITY, -INFINITY, -INFINITY, -INFINITY};
  float lr[4] = {0.f, 0.f, 0.f, 0.f};
  f32x4 o[4];
#pragma unroll
  for (int i = 0; i < 4; ++i) o[i] = f32x4{0.f, 0.f, 0.f, 0.f};

  for (int kv0 = 0; kv0 < S; kv0 += KVB) {
    // ---- scores: QK^T ----
    f32x4 sc[4];
#pragma unroll
    for (int fc = 0; fc < 4; ++fc) {
      f32x4 z = f32x4{0.f, 0.f, 0.f, 0.f};
      bf16x8 k0 = *(const bf16x8*)(Kb + (size_t)(kv0 + fc * 16 + c) * DK + g * 8);
      bf16x8 k1 = *(const bf16x8*)(Kb + (size_t)(kv0 + fc * 16 + c) * DK + 32 + g * 8);
      z = __builtin_amdgcn_mfma_f32_16x16x32_bf16(qf[0], k0, z, 0, 0, 0);
      z = __builtin_amdgcn_mfma_f32_16x16x32_bf16(qf[1], k1, z, 0, 0, 0);
      sc[fc] = z * 0.125f;  // 1/sqrt(DK)
    }
    // ---- online softmax (rows 4g+j are lane-local) ----
    float pm[4];
#pragma unroll
    for (int j = 0; j < 4; ++j) {
      float v = fmaxf(fmaxf(sc[0][j], sc[1][j]), fmaxf(sc[2][j], sc[3][j]));
#pragma unroll
      for (int d = 1; d < 16; d <<= 1) v = fmaxf(v, __shfl_xor(v, d));
      pm[j] = v;
    }
    float fsc[4], rs[4];
    float pv[4][4];
#pragma unroll
    for (int j = 0; j < 4; ++j) {
      float mn = fmaxf(mr[j], pm[j]);
      fsc[j] = __expf(mr[j] - mn);
      mr[j] = mn;
      rs[j] = 0.f;
    }
#pragma unroll
    for (int fc = 0; fc < 4; ++fc)
#pragma unroll
      for (int j = 0; j < 4; ++j) {
        float p = __expf(sc[fc][j] - mr[j]);
        pv[fc][j] = p;
        rs[j] += p;
      }
#pragma unroll
    for (int j = 0; j < 4; ++j) {
#pragma unroll
      for (int d = 1; d < 16; d <<= 1) rs[j] += __shfl_xor(rs[j], d);
      lr[j] = lr[j] * fsc[j] + rs[j];
    }
#pragma unroll
    for (int fd = 0; fd < 4; ++fd)
#pragma unroll
      for (int j = 0; j < 4; ++j) o[fd][j] *= fsc[j];
    // ---- P -> LDS (bf16, per-wave region, no cross-wave sync needed) ----
#pragma unroll
    for (int fc = 0; fc < 4; ++fc)
#pragma unroll
      for (int j = 0; j < 4; ++j)
        P[w][g * 4 + j][fc * 16 + c] = (__bf16)pv[fc][j];
    // ---- PV ----
#pragma unroll
    for (int kk = 0; kk < 2; ++kk) {
      bf16x8 pa = *(const bf16x8*)(&P[w][c][kk * 32 + g * 8]);
#pragma unroll
      for (int fd = 0; fd < 4; ++fd) {
        bf16x8 vf = *(const bf16x8*)(Vb + (size_t)(fd * 16 + c) * S + kv0 + kk * 32 + g * 8);
        o[fd] = __builtin_amdgcn_mfma_f32_16x16x32_bf16(pa, vf, o[fd], 0, 0, 0);
      }
    }
  }

  // ---- epilogue ----
  int b = bh >> 4, h = bh & 15;
#pragma unroll
  for (int fd = 0; fd < 4; ++fd)
#pragma unroll
    for (int j = 0; j < 4; ++j) {
      int s = qr + g * 4 + j;
      float val = o[fd][j] / lr[j];
      out[(size_t)(b * S + s) * D + h * 64 + fd * 16 + c] = val;
    }
}

extern "C" void kernel_launch(void* const* d_in, const int* in_sizes, int n_in,
                              void* d_out, int out_size, void* d_ws, size_t ws_size,
                              hipStream_t stream) {
  (void)in_sizes; (void)n_in; (void)out_size; (void)ws_size;
  const float* xq = (const float*)d_in[0];
  const float* xk = (const float*)d_in[1];
  const float* xv = (const float*)d_in[2];
  const float* Wq = (const float*)d_in[3];
  const float* bq = (const float*)d_in[4];
  const float* Wk = (const float*)d_in[5];
  const float* bk = (const float*)d_in[6];
  const float* Wv = (const float*)d_in[7];
  const float* bv = (const float*)d_in[8];

  char* ws = (char*)d_ws;
  const size_t MB = 1u << 20;
  __bf16* Xc[3] = {(__bf16*)(ws + 0 * MB), (__bf16*)(ws + 8 * MB), (__bf16*)(ws + 16 * MB)};
  __bf16* WT[3] = {(__bf16*)(ws + 24 * MB), (__bf16*)(ws + 26 * MB), (__bf16*)(ws + 28 * MB)};
  __bf16* Qb = (__bf16*)(ws + 30 * MB);
  __bf16* Kb = (__bf16*)(ws + 38 * MB);
  __bf16* Vt = (__bf16*)(ws + 46 * MB);

  const float* xin[3] = {xq, xk, xv};
  const float* win[3] = {Wq, Wk, Wv};
  for (int i = 0; i < 3; ++i) {
    convx<<<dim3((M * D) / (4 * 256)), 256, 0, stream>>>(xin[i], Xc[i], M * D);
    wtrans<<<dim3(D / 32, D / 32), 256, 0, stream>>>(win[i], WT[i]);
  }
  proj_gemm<<<dim3(D / TN, M / TM), 256, 0, stream>>>(Xc[0], WT[0], bq, Qb, 0);
  proj_gemm<<<dim3(D / TN, M / TM), 256, 0, stream>>>(Xc[1], WT[1], bk, Kb, 0);
  proj_gemm<<<dim3(D / TN, M / TM), 256, 0, stream>>>(Xc[2], WT[2], bv, Vt, 1);
  attn<<<dim3(S / QBLK, BH), 256, 0, stream>>>(Qb, Kb, Vt, (float*)d_out);
}

// Round 2
// 188.293 us; speedup vs baseline: 1.7856x; 1.7856x over previous
//
#include <hip/hip_runtime.h>
#include <hip/hip_bf16.h>

typedef __bf16 bf16x4 __attribute__((ext_vector_type(4)));
typedef __bf16 bf16x8 __attribute__((ext_vector_type(8)));
typedef float  f32x4  __attribute__((ext_vector_type(4)));
typedef float  f32x16 __attribute__((ext_vector_type(16)));

constexpr int B = 2, S = 2048, D = 1024, H = 16, DK = 64;
constexpr int M = B * S;   // 4096 projection rows
constexpr int BH = B * H;  // 32

__device__ inline float fexp2(float x) {
#if __has_builtin(__builtin_amdgcn_exp2f)
  return __builtin_amdgcn_exp2f(x);
#else
  return exp2f(x);
#endif
}
__device__ inline float frcp(float x) {
#if __has_builtin(__builtin_amdgcn_rcpf)
  return __builtin_amdgcn_rcpf(x);
#else
  return 1.0f / x;
#endif
}
__device__ inline unsigned pk2(float lo, float hi) {
  union { __bf16 h[2]; unsigned u; } x;
  x.h[0] = (__bf16)lo; x.h[1] = (__bf16)hi;
  return x.u;
}

// ---------------- f32 -> bf16 convert (vectorized) ----------------
__global__ __launch_bounds__(256) void convx(const float* __restrict__ in,
                                             __bf16* __restrict__ out, int n) {
  int i = (blockIdx.x * 256 + threadIdx.x) * 4;
  if (i >= n) return;
  float4 v = *(const float4*)(in + i);
  bf16x4 o;
  o[0] = (__bf16)v.x; o[1] = (__bf16)v.y; o[2] = (__bf16)v.z; o[3] = (__bf16)v.w;
  *(bf16x4*)(out + i) = o;
}

// ---------------- W [K][N] f32 -> WT [N][K] bf16 ----------------
__global__ __launch_bounds__(256) void wtrans(const float* __restrict__ W,
                                              __bf16* __restrict__ WT) {
  __shared__ float t[32][33];
  int tx = threadIdx.x & 31, ty0 = threadIdx.x >> 5;  // 32 x 8
  int n0 = blockIdx.x * 32, k0 = blockIdx.y * 32;
#pragma unroll
  for (int i = 0; i < 4; ++i)
    t[ty0 + i * 8][tx] = W[(size_t)(k0 + ty0 + i * 8) * D + n0 + tx];
  __syncthreads();
#pragma unroll
  for (int i = 0; i < 4; ++i)
    WT[(size_t)(n0 + ty0 + i * 8) * D + k0 + tx] = (__bf16)t[tx][ty0 + i * 8];
}

// ---------------- merged projection GEMMs ----------------
// z=0: Q (scaled by 0.125*log2e), z=1: K, z=2: V (transposed out)
constexpr int TM = 128, TN = 128, BK = 32;

__global__ __launch_bounds__(256) void proj3(
    const __bf16* __restrict__ X0, const __bf16* __restrict__ X1,
    const __bf16* __restrict__ X2, const __bf16* __restrict__ W0,
    const __bf16* __restrict__ W1, const __bf16* __restrict__ W2,
    const float* __restrict__ b0, const float* __restrict__ b1,
    const float* __restrict__ b2, __bf16* __restrict__ Qo,
    __bf16* __restrict__ Ko, __bf16* __restrict__ Vo) {
  __shared__ __align__(16) __bf16 As[TM * BK];
  __shared__ __align__(16) __bf16 Bs[TN * BK];
  int z = blockIdx.z;
  const __bf16* A  = z == 0 ? X0 : z == 1 ? X1 : X2;
  const __bf16* BT = z == 0 ? W0 : z == 1 ? W1 : W2;
  const float* bias = z == 0 ? b0 : z == 1 ? b1 : b2;
  __bf16* out = z == 0 ? Qo : z == 1 ? Ko : Vo;
  int mode = (z == 2) ? 1 : 0;
  float osc = (z == 0) ? 0.18033688011112042f : 1.0f;  // 0.125 * log2(e)

  int t = threadIdx.x;
  int m0 = blockIdx.y * TM, n0 = blockIdx.x * TN;
  int w = t >> 6, lane = t & 63, c = lane & 15, g = lane >> 4;
  int wr = w >> 1, wc = w & 1;

  f32x4 acc[4][4];
#pragma unroll
  for (int i = 0; i < 4; ++i)
#pragma unroll
    for (int j = 0; j < 4; ++j) acc[i][j] = f32x4{0.f, 0.f, 0.f, 0.f};

  int srow = t >> 2;
  int scol = (t & 3) * 8;
  const __bf16* ag = A + (size_t)(m0 + srow) * D + scol;
  const __bf16* bg = BT + (size_t)(n0 + srow) * D + scol;

  for (int kk = 0; kk < D; kk += BK) {
    __builtin_amdgcn_global_load_lds(
        (const __attribute__((address_space(1))) unsigned int*)(ag + kk),
        (__attribute__((address_space(3))) unsigned int*)(As + t * 8), 16, 0, 0);
    __builtin_amdgcn_global_load_lds(
        (const __attribute__((address_space(1))) unsigned int*)(ag + (size_t)64 * D + kk),
        (__attribute__((address_space(3))) unsigned int*)(As + 2048 + t * 8), 16, 0, 0);
    __builtin_amdgcn_global_load_lds(
        (const __attribute__((address_space(1))) unsigned int*)(bg + kk),
        (__attribute__((address_space(3))) unsigned int*)(Bs + t * 8), 16, 0, 0);
    __builtin_amdgcn_global_load_lds(
        (const __attribute__((address_space(1))) unsigned int*)(bg + (size_t)64 * D + kk),
        (__attribute__((address_space(3))) unsigned int*)(Bs + 2048 + t * 8), 16, 0, 0);
    __syncthreads();

    bf16x8 af[4], bf[4];
#pragma unroll
    for (int i = 0; i < 4; ++i)
      af[i] = *(const bf16x8*)(As + (wr * 64 + i * 16 + c) * 32 + g * 8);
#pragma unroll
    for (int j = 0; j < 4; ++j)
      bf[j] = *(const bf16x8*)(Bs + (wc * 64 + j * 16 + c) * 32 + g * 8);
#pragma unroll
    for (int i = 0; i < 4; ++i)
#pragma unroll
      for (int j = 0; j < 4; ++j)
        acc[i][j] = __builtin_amdgcn_mfma_f32_16x16x32_bf16(af[i], bf[j], acc[i][j], 0, 0, 0);
    __syncthreads();
  }

#pragma unroll
  for (int i = 0; i < 4; ++i)
#pragma unroll
    for (int j = 0; j < 4; ++j) {
      int n = n0 + wc * 64 + j * 16 + c;
      float bv = bias[n];
      int h = n >> 6, dk = n & 63;
#pragma unroll
      for (int q = 0; q < 4; ++q) {
        int mrow = m0 + wr * 64 + i * 16 + g * 4 + q;
        int b = mrow >> 11, s = mrow & (S - 1);
        float val = (acc[i][j][q] + bv) * osc;
        size_t idx;
        if (mode == 0) idx = ((size_t)(b * H + h) * S + s) * DK + dk;
        else           idx = ((size_t)(b * H + h) * DK + dk) * S + s;
        out[idx] = (__bf16)val;
      }
    }
}

// ---------------- flash attention, swapped-QK^T 32x32 ----------------
// Q,K: [BH][S][DK] bf16 (Q pre-scaled by 0.125*log2e); VT: [BH][DK][S] bf16
// out: [B][S][D] f32
constexpr int NT = S / 32;  // 64 kv tiles of 32

__global__ __launch_bounds__(256, 2) void attn(const __bf16* __restrict__ Q,
                                               const __bf16* __restrict__ K,
                                               const __bf16* __restrict__ VT,
                                               float* __restrict__ out) {
  int t = threadIdx.x, w = t >> 6, lane = t & 63;
  int l31 = lane & 31, hi = lane >> 5;
  int bh = blockIdx.y;
  int q0 = blockIdx.x * 128 + w * 32;
  const __bf16* Qb = Q + (size_t)bh * S * DK;
  const __bf16* Kb = K + (size_t)bh * S * DK;
  const __bf16* Vb = VT + (size_t)bh * DK * S;

  // Q B-fragments: lane holds q=q0+l31, dk = s*16 + hi*8 + [0..7]
  bf16x8 qf[4];
  {
    const __bf16* qp = Qb + (size_t)(q0 + l31) * DK + hi * 8;
#pragma unroll
    for (int s2 = 0; s2 < 4; ++s2) qf[s2] = *(const bf16x8*)(qp + s2 * 16);
  }

  f32x16 acc0, acc1;
#pragma unroll
  for (int r = 0; r < 16; ++r) { acc0[r] = 0.f; acc1[r] = 0.f; }
  float mrun = -1e30f, lrun = 0.f;

  bf16x8 KA[4], VA[4], KB[4], VB[4];

  auto loadKV = [&](int tt, bf16x8* Kf, bf16x8* Vf) {
    const __bf16* kp = Kb + (size_t)(tt * 32 + l31) * DK + hi * 8;
#pragma unroll
    for (int s2 = 0; s2 < 4; ++s2) Kf[s2] = *(const bf16x8*)(kp + s2 * 16);
#pragma unroll
    for (int ks = 0; ks < 2; ++ks)
#pragma unroll
      for (int db = 0; db < 2; ++db)
        Vf[ks * 2 + db] =
            *(const bf16x8*)(Vb + (size_t)(db * 32 + l31) * S + tt * 32 + ks * 16 + hi * 8);
  };

  auto compute = [&](bf16x8* Kf, bf16x8* Vf) {
    // S^T tile: row kv=(r&3)+8*(r>>2)+4*hi, col q=l31 (log2-domain scores)
    f32x16 st;
#pragma unroll
    for (int r = 0; r < 16; ++r) st[r] = 0.f;
#pragma unroll
    for (int s2 = 0; s2 < 4; ++s2)
      st = __builtin_amdgcn_mfma_f32_32x32x16_bf16(Kf[s2], qf[s2], st, 0, 0, 0);

    float pmax = st[0];
#pragma unroll
    for (int r = 1; r < 16; ++r) pmax = fmaxf(pmax, st[r]);
    pmax = fmaxf(pmax, __shfl_xor(pmax, 32));

    if (__any(pmax > mrun + 11.5f)) {  // defer-max: THR = 8 nats in log2 units
      float mn = fmaxf(mrun, pmax);
      float fs = fexp2(mrun - mn);
#pragma unroll
      for (int r = 0; r < 16; ++r) {
        float f = __shfl(fs, (r & 3) + 8 * (r >> 2) + 4 * hi);
        acc0[r] *= f; acc1[r] *= f;
      }
      lrun *= fs;
      mrun = mn;
    }

    float p[16];
    float ts = 0.f;
#pragma unroll
    for (int r = 0; r < 16; ++r) { p[r] = fexp2(st[r] - mrun); ts += p[r]; }
    ts += __shfl_xor(ts, 32);
    lrun += ts;

    // pack P -> bf16 A-fragments (kv-local layout -> hi*8+j contiguous)
    unsigned a01 = pk2(p[0], p[1]),   a23 = pk2(p[2], p[3]);
    unsigned a45 = pk2(p[4], p[5]),   a67 = pk2(p[6], p[7]);
    unsigned b01 = pk2(p[8], p[9]),   b23 = pk2(p[10], p[11]);
    unsigned b45 = pk2(p[12], p[13]), b67 = pk2(p[14], p[15]);
    unsigned xa01 = (unsigned)__shfl_xor((int)a01, 32);
    unsigned xa23 = (unsigned)__shfl_xor((int)a23, 32);
    unsigned xa45 = (unsigned)__shfl_xor((int)a45, 32);
    unsigned xa67 = (unsigned)__shfl_xor((int)a67, 32);
    unsigned xb01 = (unsigned)__shfl_xor((int)b01, 32);
    unsigned xb23 = (unsigned)__shfl_xor((int)b23, 32);
    unsigned xb45 = (unsigned)__shfl_xor((int)b45, 32);
    unsigned xb67 = (unsigned)__shfl_xor((int)b67, 32);
    union Pk { unsigned u[4]; bf16x8 v; } P0, P1;
    P0.u[0] = hi ? xa45 : a01;  P0.u[1] = hi ? xa67 : a23;
    P0.u[2] = hi ? a45 : xa01;  P0.u[3] = hi ? a67 : xa23;
    P1.u[0] = hi ? xb45 : b01;  P1.u[1] = hi ? xb67 : b23;
    P1.u[2] = hi ? b45 : xb01;  P1.u[3] = hi ? b67 : xb23;

    acc0 = __builtin_amdgcn_mfma_f32_32x32x16_bf16(P0.v, Vf[0], acc0, 0, 0, 0);
    acc1 = __builtin_amdgcn_mfma_f32_32x32x16_bf16(P0.v, Vf[1], acc1, 0, 0, 0);
    acc0 = __builtin_amdgcn_mfma_f32_32x32x16_bf16(P1.v, Vf[2], acc0, 0, 0, 0);
    acc1 = __builtin_amdgcn_mfma_f32_32x32x16_bf16(P1.v, Vf[3], acc1, 0, 0, 0);
  };

  loadKV(0, KA, VA);
  for (int tt = 0; tt < NT; tt += 2) {
    loadKV(tt + 1, KB, VB);
    compute(KA, VA);
    loadKV(tt + 2 < NT ? tt + 2 : NT - 1, KA, VA);
    compute(KB, VB);
  }

  // epilogue: out[b][s][h*64 + db*32 + d]
  int b = bh >> 4, h = bh & 15;
#pragma unroll
  for (int r = 0; r < 16; ++r) {
    int rowq = (r & 3) + 8 * (r >> 2) + 4 * hi;
    float li = __shfl(lrun, rowq);
    float ri = frcp(li);
    size_t base = (size_t)(b * S + q0 + rowq) * D + h * 64 + l31;
    out[base] = acc0[r] * ri;
    out[base + 32] = acc1[r] * ri;
  }
}

extern "C" void kernel_launch(void* const* d_in, const int* in_sizes, int n_in,
                              void* d_out, int out_size, void* d_ws, size_t ws_size,
                              hipStream_t stream) {
  (void)in_sizes; (void)n_in; (void)out_size; (void)ws_size;
  const float* xq = (const float*)d_in[0];
  const float* xk = (const float*)d_in[1];
  const float* xv = (const float*)d_in[2];
  const float* Wq = (const float*)d_in[3];
  const float* bq = (const float*)d_in[4];
  const float* Wk = (const float*)d_in[5];
  const float* bk = (const float*)d_in[6];
  const float* Wv = (const float*)d_in[7];
  const float* bv = (const float*)d_in[8];

  char* ws = (char*)d_ws;
  const size_t MB = 1u << 20;
  __bf16* Xc[3] = {(__bf16*)(ws + 0 * MB), (__bf16*)(ws + 8 * MB), (__bf16*)(ws + 16 * MB)};
  __bf16* WT[3] = {(__bf16*)(ws + 24 * MB), (__bf16*)(ws + 26 * MB), (__bf16*)(ws + 28 * MB)};
  __bf16* Qb = (__bf16*)(ws + 30 * MB);
  __bf16* Kb = (__bf16*)(ws + 38 * MB);
  __bf16* Vt = (__bf16*)(ws + 46 * MB);

  const float* xin[3] = {xq, xk, xv};
  const float* win[3] = {Wq, Wk, Wv};
  for (int i = 0; i < 3; ++i) {
    convx<<<dim3((M * D) / (4 * 256)), 256, 0, stream>>>(xin[i], Xc[i], M * D);
    wtrans<<<dim3(D / 32, D / 32), 256, 0, stream>>>(win[i], WT[i]);
  }
  proj3<<<dim3(D / TN, M / TM, 3), 256, 0, stream>>>(Xc[0], Xc[1], Xc[2],
                                                     WT[0], WT[1], WT[2],
                                                     bq, bk, bv, Qb, Kb, Vt);
  attn<<<dim3(S / 128, BH), 256, 0, stream>>>(Qb, Kb, Vt, (float*)d_out);
}

// Round 4
// 127.002 us; speedup vs baseline: 2.6473x; 1.4826x over previous
//
#include <hip/hip_runtime.h>
#include <hip/hip_bf16.h>

typedef __bf16 bf16x4 __attribute__((ext_vector_type(4)));
typedef __bf16 bf16x8 __attribute__((ext_vector_type(8)));
typedef float  f32x4  __attribute__((ext_vector_type(4)));
typedef float  f32x16 __attribute__((ext_vector_type(16)));

constexpr int B = 2, S = 2048, D = 1024, H = 16, DK = 64;
constexpr int M = B * S;
constexpr int BH = B * H;

__device__ inline float fexp2(float x) {
#if __has_builtin(__builtin_amdgcn_exp2f)
  return __builtin_amdgcn_exp2f(x);
#else
  return exp2f(x);
#endif
}
__device__ inline float frcp(float x) {
#if __has_builtin(__builtin_amdgcn_rcpf)
  return __builtin_amdgcn_rcpf(x);
#else
  return 1.0f / x;
#endif
}
__device__ inline unsigned pk2(float lo, float hi) {
  union { __bf16 h[2]; unsigned u; } x;
  x.h[0] = (__bf16)lo; x.h[1] = (__bf16)hi;
  return x.u;
}

// ---------------- f32 -> bf16 convert, 3 tensors in one launch ----------------
__global__ __launch_bounds__(256) void convx3(const float* __restrict__ x0,
                                              const float* __restrict__ x1,
                                              const float* __restrict__ x2,
                                              __bf16* __restrict__ o0,
                                              __bf16* __restrict__ o1,
                                              __bf16* __restrict__ o2) {
  int z = blockIdx.y;
  const float* in = z == 0 ? x0 : z == 1 ? x1 : x2;
  __bf16* out = z == 0 ? o0 : z == 1 ? o1 : o2;
  int i = (blockIdx.x * 256 + threadIdx.x) * 4;
  float4 v = *(const float4*)(in + i);
  bf16x4 o;
  o[0] = (__bf16)v.x; o[1] = (__bf16)v.y; o[2] = (__bf16)v.z; o[3] = (__bf16)v.w;
  *(bf16x4*)(out + i) = o;
}

// ---------------- W [K][N] f32 -> WT [N][K] bf16, 3 in one launch ----------------
__global__ __launch_bounds__(256) void wtrans3(const float* __restrict__ w0,
                                               const float* __restrict__ w1,
                                               const float* __restrict__ w2,
                                               __bf16* __restrict__ t0,
                                               __bf16* __restrict__ t1,
                                               __bf16* __restrict__ t2) {
  int z = blockIdx.z;
  const float* W = z == 0 ? w0 : z == 1 ? w1 : w2;
  __bf16* WT = z == 0 ? t0 : z == 1 ? t1 : t2;
  __shared__ float t[32][33];
  int tx = threadIdx.x & 31, ty0 = threadIdx.x >> 5;
  int n0 = blockIdx.x * 32, k0 = blockIdx.y * 32;
#pragma unroll
  for (int i = 0; i < 4; ++i)
    t[ty0 + i * 8][tx] = W[(size_t)(k0 + ty0 + i * 8) * D + n0 + tx];
  __syncthreads();
#pragma unroll
  for (int i = 0; i < 4; ++i)
    WT[(size_t)(n0 + ty0 + i * 8) * D + k0 + tx] = (__bf16)t[tx][ty0 + i * 8];
}

// ---------------- merged projection GEMMs ----------------
constexpr int TM = 128, TN = 128, BK = 32;

__global__ __launch_bounds__(256) void proj3(
    const __bf16* __restrict__ X0, const __bf16* __restrict__ X1,
    const __bf16* __restrict__ X2, const __bf16* __restrict__ W0,
    const __bf16* __restrict__ W1, const __bf16* __restrict__ W2,
    const float* __restrict__ b0, const float* __restrict__ b1,
    const float* __restrict__ b2, __bf16* __restrict__ Qo,
    __bf16* __restrict__ Ko, __bf16* __restrict__ Vo) {
  __shared__ __align__(16) __bf16 As[TM * BK];
  __shared__ __align__(16) __bf16 Bs[TN * BK];
  int z = blockIdx.z;
  const __bf16* A  = z == 0 ? X0 : z == 1 ? X1 : X2;
  const __bf16* BT = z == 0 ? W0 : z == 1 ? W1 : W2;
  const float* bias = z == 0 ? b0 : z == 1 ? b1 : b2;
  __bf16* out = z == 0 ? Qo : z == 1 ? Ko : Vo;
  int mode = (z == 2) ? 1 : 0;
  float osc = (z == 0) ? 0.18033688011112042f : 1.0f;  // 0.125 * log2(e)

  int t = threadIdx.x;
  int m0 = blockIdx.y * TM, n0 = blockIdx.x * TN;
  int w = t >> 6, lane = t & 63, c = lane & 15, g = lane >> 4;
  int wr = w >> 1, wc = w & 1;

  f32x4 acc[4][4];
#pragma unroll
  for (int i = 0; i < 4; ++i)
#pragma unroll
    for (int j = 0; j < 4; ++j) acc[i][j] = f32x4{0.f, 0.f, 0.f, 0.f};

  int srow = t >> 2;
  int scol = (t & 3) * 8;
  const __bf16* ag = A + (size_t)(m0 + srow) * D + scol;
  const __bf16* bg = BT + (size_t)(n0 + srow) * D + scol;

  for (int kk = 0; kk < D; kk += BK) {
    __builtin_amdgcn_global_load_lds(
        (const __attribute__((address_space(1))) unsigned int*)(ag + kk),
        (__attribute__((address_space(3))) unsigned int*)(As + t * 8), 16, 0, 0);
    __builtin_amdgcn_global_load_lds(
        (const __attribute__((address_space(1))) unsigned int*)(ag + (size_t)64 * D + kk),
        (__attribute__((address_space(3))) unsigned int*)(As + 2048 + t * 8), 16, 0, 0);
    __builtin_amdgcn_global_load_lds(
        (const __attribute__((address_space(1))) unsigned int*)(bg + kk),
        (__attribute__((address_space(3))) unsigned int*)(Bs + t * 8), 16, 0, 0);
    __builtin_amdgcn_global_load_lds(
        (const __attribute__((address_space(1))) unsigned int*)(bg + (size_t)64 * D + kk),
        (__attribute__((address_space(3))) unsigned int*)(Bs + 2048 + t * 8), 16, 0, 0);
    __syncthreads();

    bf16x8 af[4], bf[4];
#pragma unroll
    for (int i = 0; i < 4; ++i)
      af[i] = *(const bf16x8*)(As + (wr * 64 + i * 16 + c) * 32 + g * 8);
#pragma unroll
    for (int j = 0; j < 4; ++j)
      bf[j] = *(const bf16x8*)(Bs + (wc * 64 + j * 16 + c) * 32 + g * 8);
#pragma unroll
    for (int i = 0; i < 4; ++i)
#pragma unroll
      for (int j = 0; j < 4; ++j)
        acc[i][j] = __builtin_amdgcn_mfma_f32_16x16x32_bf16(af[i], bf[j], acc[i][j], 0, 0, 0);
    __syncthreads();
  }

#pragma unroll
  for (int i = 0; i < 4; ++i)
#pragma unroll
    for (int j = 0; j < 4; ++j) {
      int n = n0 + wc * 64 + j * 16 + c;
      float bv = bias[n];
      int h = n >> 6, dk = n & 63;
#pragma unroll
      for (int q = 0; q < 4; ++q) {
        int mrow = m0 + wr * 64 + i * 16 + g * 4 + q;
        int b = mrow >> 11, s = mrow & (S - 1);
        float val = (acc[i][j][q] + bv) * osc;
        size_t idx;
        if (mode == 0) idx = ((size_t)(b * H + h) * S + s) * DK + dk;
        else           idx = ((size_t)(b * H + h) * DK + dk) * S + s;
        out[idx] = (__bf16)val;
      }
    }
}

// ---------------- flash attention, LDS-staged K/V ----------------
// Q,K: [BH][S][DK] bf16 (Q pre-scaled by 0.125*log2e); VT: [BH][DK][S] bf16
// out: [B][S][D] f32
constexpr int NSTEP = S / 64;  // 32 KV steps of 64

__global__ __launch_bounds__(256) void attn(const __bf16* __restrict__ Q,
                                            const __bf16* __restrict__ K,
                                            const __bf16* __restrict__ VT,
                                            float* __restrict__ out) {
  // swizzled tiles: [64 rows][128 bytes], byte ^= ((row&7)<<4)
  __shared__ __align__(16) __bf16 Ks[2][4096];
  __shared__ __align__(16) __bf16 Vs[2][4096];

  int t = threadIdx.x, w = t >> 6, lane = t & 63;
  int l31 = lane & 31, hi = lane >> 5;

  // XCD-bijective swizzle: 512 blocks, 8 XCDs, each XCD owns 4 heads
  int fid = blockIdx.x;
  int xcd = fid & 7, slot = fid >> 3;
  int bh = xcd * 4 + (slot >> 4);
  int q0 = (slot & 15) * 128 + w * 32;

  const __bf16* Qb = Q + (size_t)bh * S * DK;
  const char* Kg = (const char*)(K + (size_t)bh * S * DK);
  const char* Vg = (const char*)(VT + (size_t)bh * DK * S);

  // Q B-fragments: lane holds q=q0+l31, dk = s2*16 + hi*8 + [0..7]
  bf16x8 qf[4];
  {
    const __bf16* qp = Qb + (size_t)(q0 + l31) * DK + hi * 8;
#pragma unroll
    for (int s2 = 0; s2 < 4; ++s2) qf[s2] = *(const bf16x8*)(qp + s2 * 16);
  }

  f32x16 acc0, acc1;
#pragma unroll
  for (int r = 0; r < 16; ++r) { acc0[r] = 0.f; acc1[r] = 0.f; }
  float mrun = -1e30f, lrun = 0.f;

  int swz = (l31 & 7) << 4;

  // stage K/V tile tt into buffer bufi (source-side inverse swizzle, linear LDS dest)
  auto stage = [&](int bufi, int tt) {
#pragma unroll
    for (int i = 0; i < 2; ++i) {
      int L = i * 4096 + t * 16;
      int row = L >> 7;
      int sz = (row & 7) << 4;
      __builtin_amdgcn_global_load_lds(
          (const __attribute__((address_space(1))) unsigned int*)(Kg + (size_t)tt * 8192 + (L ^ sz)),
          (__attribute__((address_space(3))) unsigned int*)((char*)&Ks[bufi][0] + L), 16, 0, 0);
      __builtin_amdgcn_global_load_lds(
          (const __attribute__((address_space(1))) unsigned int*)(Vg + (size_t)row * (S * 2) + tt * 128 + ((L & 127) ^ sz)),
          (__attribute__((address_space(3))) unsigned int*)((char*)&Vs[bufi][0] + L), 16, 0, 0);
    }
  };

  stage(0, 0);
  __syncthreads();

  for (int tt = 0; tt < NSTEP; ++tt) {
    int cur = tt & 1;
    if (tt + 1 < NSTEP) stage(cur ^ 1, tt + 1);
    const char* kb = (const char*)&Ks[cur][0];
    const char* vb = (const char*)&Vs[cur][0];

#pragma unroll
    for (int sub = 0; sub < 2; ++sub) {
      bf16x8 Kf[4], Vf[4];
      {
        const char* kr = kb + ((sub * 32 + l31) << 7);
#pragma unroll
        for (int s2 = 0; s2 < 4; ++s2)
          Kf[s2] = *(const bf16x8*)(kr + ((s2 * 32 + hi * 16) ^ swz));
      }
#pragma unroll
      for (int ks = 0; ks < 2; ++ks)
#pragma unroll
        for (int db = 0; db < 2; ++db)
          Vf[ks * 2 + db] = *(const bf16x8*)(vb + ((db * 32 + l31) << 7) +
                                             ((sub * 64 + ks * 32 + hi * 16) ^ swz));

      // S^T tile (log2-domain scores): row kv=(r&3)+8*(r>>2)+4*hi, col q=l31
      f32x16 st;
#pragma unroll
      for (int r = 0; r < 16; ++r) st[r] = 0.f;
#pragma unroll
      for (int s2 = 0; s2 < 4; ++s2)
        st = __builtin_amdgcn_mfma_f32_32x32x16_bf16(Kf[s2], qf[s2], st, 0, 0, 0);

      // ---- round-2-verified softmax/pack (shfl-based) ----
      float pmax = st[0];
#pragma unroll
      for (int r = 1; r < 16; ++r) pmax = fmaxf(pmax, st[r]);
      pmax = fmaxf(pmax, __shfl_xor(pmax, 32));

      if (__any(pmax > mrun + 11.5f)) {  // defer-max
        float mn = fmaxf(mrun, pmax);
        float fs = fexp2(mrun - mn);
#pragma unroll
        for (int r = 0; r < 16; ++r) {
          float f = __shfl(fs, (r & 3) + 8 * (r >> 2) + 4 * hi);
          acc0[r] *= f; acc1[r] *= f;
        }
        lrun *= fs;
        mrun = mn;
      }

      float p[16];
      float ts = 0.f;
#pragma unroll
      for (int r = 0; r < 16; ++r) { p[r] = fexp2(st[r] - mrun); ts += p[r]; }
      ts += __shfl_xor(ts, 32);
      lrun += ts;

      unsigned a01 = pk2(p[0], p[1]),   a23 = pk2(p[2], p[3]);
      unsigned a45 = pk2(p[4], p[5]),   a67 = pk2(p[6], p[7]);
      unsigned b01 = pk2(p[8], p[9]),   b23 = pk2(p[10], p[11]);
      unsigned b45 = pk2(p[12], p[13]), b67 = pk2(p[14], p[15]);
      unsigned xa01 = (unsigned)__shfl_xor((int)a01, 32);
      unsigned xa23 = (unsigned)__shfl_xor((int)a23, 32);
      unsigned xa45 = (unsigned)__shfl_xor((int)a45, 32);
      unsigned xa67 = (unsigned)__shfl_xor((int)a67, 32);
      unsigned xb01 = (unsigned)__shfl_xor((int)b01, 32);
      unsigned xb23 = (unsigned)__shfl_xor((int)b23, 32);
      unsigned xb45 = (unsigned)__shfl_xor((int)b45, 32);
      unsigned xb67 = (unsigned)__shfl_xor((int)b67, 32);
      union Pk { unsigned u[4]; bf16x8 v; } P0, P1;
      P0.u[0] = hi ? xa45 : a01;  P0.u[1] = hi ? xa67 : a23;
      P0.u[2] = hi ? a45 : xa01;  P0.u[3] = hi ? a67 : xa23;
      P1.u[0] = hi ? xb45 : b01;  P1.u[1] = hi ? xb67 : b23;
      P1.u[2] = hi ? b45 : xb01;  P1.u[3] = hi ? b67 : xb23;

      acc0 = __builtin_amdgcn_mfma_f32_32x32x16_bf16(P0.v, Vf[0], acc0, 0, 0, 0);
      acc1 = __builtin_amdgcn_mfma_f32_32x32x16_bf16(P0.v, Vf[1], acc1, 0, 0, 0);
      acc0 = __builtin_amdgcn_mfma_f32_32x32x16_bf16(P1.v, Vf[2], acc0, 0, 0, 0);
      acc1 = __builtin_amdgcn_mfma_f32_32x32x16_bf16(P1.v, Vf[3], acc1, 0, 0, 0);
    }
    __syncthreads();
  }

  // epilogue: out[b][s][h*64 + db*32 + d]
  int b = bh >> 4, h = bh & 15;
#pragma unroll
  for (int r = 0; r < 16; ++r) {
    int rowq = (r & 3) + 8 * (r >> 2) + 4 * hi;
    float li = __shfl(lrun, rowq);
    float ri = frcp(li);
    size_t base = (size_t)(b * S + q0 + rowq) * D + h * 64 + l31;
    out[base] = acc0[r] * ri;
    out[base + 32] = acc1[r] * ri;
  }
}

extern "C" void kernel_launch(void* const* d_in, const int* in_sizes, int n_in,
                              void* d_out, int out_size, void* d_ws, size_t ws_size,
                              hipStream_t stream) {
  (void)in_sizes; (void)n_in; (void)out_size; (void)ws_size;
  const float* xq = (const float*)d_in[0];
  const float* xk = (const float*)d_in[1];
  const float* xv = (const float*)d_in[2];
  const float* Wq = (const float*)d_in[3];
  const float* bq = (const float*)d_in[4];
  const float* Wk = (const float*)d_in[5];
  const float* bk = (const float*)d_in[6];
  const float* Wv = (const float*)d_in[7];
  const float* bv = (const float*)d_in[8];

  char* ws = (char*)d_ws;
  const size_t MB = 1u << 20;
  __bf16* Xc[3] = {(__bf16*)(ws + 0 * MB), (__bf16*)(ws + 8 * MB), (__bf16*)(ws + 16 * MB)};
  __bf16* WT[3] = {(__bf16*)(ws + 24 * MB), (__bf16*)(ws + 26 * MB), (__bf16*)(ws + 28 * MB)};
  __bf16* Qb = (__bf16*)(ws + 30 * MB);
  __bf16* Kb = (__bf16*)(ws + 38 * MB);
  __bf16* Vt = (__bf16*)(ws + 46 * MB);

  convx3<<<dim3((M * D) / (4 * 256), 3), 256, 0, stream>>>(xq, xk, xv, Xc[0], Xc[1], Xc[2]);
  wtrans3<<<dim3(D / 32, D / 32, 3), 256, 0, stream>>>(Wq, Wk, Wv, WT[0], WT[1], WT[2]);
  proj3<<<dim3(D / TN, M / TM, 3), 256, 0, stream>>>(Xc[0], Xc[1], Xc[2],
                                                     WT[0], WT[1], WT[2],
                                                     bq, bk, bv, Qb, Kb, Vt);
  attn<<<dim3(512), 256, 0, stream>>>(Qb, Kb, Vt, (float*)d_out);
}